// Round 14
// baseline (123846.838 us; speedup 1.0000x reference)
//
// R14: persistent + LDS-resident weights (R13) with a rebuilt compute core:
//  - 4 cols/thread register tiling (A cvt + A traffic amortized x4)
//  - activations stored TRANSPOSED A_T[k][row] -> lane(=row) reads coalesce
//  - W in LDS column-major UNSWIZZLED: serial-k threads => all lanes read the
//    same W address = broadcast, conflict-free by construction
//  - inputsT[t][k][b] transposed once at start (32MB in ws)
// Same fp64 accumulate, same ascending-k fma order -> absmax 0.015625 expected.
#include <hip/hip_runtime.h>
#include <math.h>

#define T_ 128
#define NBLK 256
#define NTHR 1024

__device__ __forceinline__ double sigm_d(double x) { return 1.0 / (1.0 + exp(-x)); }

// ---- software grid barrier (R12-proven) ----
__device__ __forceinline__ void gsync(unsigned* cnt, unsigned* gen) {
  __syncthreads();
  if (threadIdx.x == 0) {
    __threadfence();
    unsigned g = __hip_atomic_load(gen, __ATOMIC_RELAXED, __HIP_MEMORY_SCOPE_AGENT);
    unsigned a = __hip_atomic_fetch_add(cnt, 1u, __ATOMIC_ACQ_REL, __HIP_MEMORY_SCOPE_AGENT);
    if (a == NBLK - 1u) {
      __hip_atomic_store(cnt, 0u, __ATOMIC_RELAXED, __HIP_MEMORY_SCOPE_AGENT);
      __hip_atomic_store(gen, g + 1u, __ATOMIC_RELEASE, __HIP_MEMORY_SCOPE_AGENT);
    } else {
      while (__hip_atomic_load(gen, __ATOMIC_RELAXED, __HIP_MEMORY_SCOPE_AGENT) == g)
        __builtin_amdgcn_s_sleep(2);
      (void)__hip_atomic_load(gen, __ATOMIC_ACQUIRE, __HIP_MEMORY_SCOPE_AGENT);
    }
  }
  __syncthreads();
}

// ---- 4-col dot: A_T[k][row] (fp32, global) x 4 LDS W cols (column-major) ----
// Ascending-k fma order identical to R13's dotWL -> bit-identical results.
__device__ __forceinline__ void dot4(const float* __restrict__ AT, int ldr, int row,
                                     const float* __restrict__ W4, double a[4]) {
  a[0] = a[1] = a[2] = a[3] = 0.0;
#pragma unroll 4
  for (int k = 0; k < 1024; k += 4) {
    double d0 = (double)AT[(size_t)(k + 0) * ldr + row];
    double d1 = (double)AT[(size_t)(k + 1) * ldr + row];
    double d2 = (double)AT[(size_t)(k + 2) * ldr + row];
    double d3 = (double)AT[(size_t)(k + 3) * ldr + row];
#pragma unroll
    for (int j = 0; j < 4; ++j) {
      float4 w = *(const float4*)(W4 + j * 1024 + k);   // wave-uniform: broadcast
      a[j] = fma(d3, (double)w.w, fma(d2, (double)w.z,
             fma(d1, (double)w.y, fma(d0, (double)w.x, a[j]))));
    }
  }
}

// ---- 1-col dot (phases C/D/E) ----
__device__ __forceinline__ double dot1(const float* __restrict__ AT, int ldr, int row,
                                       const float* __restrict__ Wc) {
  double a = 0.0;
#pragma unroll 8
  for (int k = 0; k < 1024; k += 4) {
    float4 w = *(const float4*)(Wc + k);
    a = fma((double)AT[(size_t)(k + 0) * ldr + row], (double)w.x, a);
    a = fma((double)AT[(size_t)(k + 1) * ldr + row], (double)w.y, a);
    a = fma((double)AT[(size_t)(k + 2) * ldr + row], (double)w.z, a);
    a = fma((double)AT[(size_t)(k + 3) * ldr + row], (double)w.w, a);
  }
  return a;
}

// ---- stage W slice into LDS, column-major: dst[j*1024 + k] = G[k][col0+j] ----
__device__ __forceinline__ void loadW(const float* __restrict__ G, int ldw,
                                      int col0, int ncol, float* __restrict__ dst) {
  for (int i = threadIdx.x; i < (ncol << 10); i += NTHR) {
    int j = i >> 10, k = i & 1023;
    dst[j * 1024 + k] = G[(size_t)k * ldw + col0 + j];
  }
}

// ---- transpose inputs[b][t][k] -> inputsT[t][k][b] (one-time) ----
__global__ __launch_bounds__(256) void k_trans(const float* __restrict__ in,
                                               float* __restrict__ inT) {
  __shared__ float tile[64][65];
  int t = blockIdx.y, k0 = blockIdx.x * 64;
  int x = threadIdx.x & 63, y4 = threadIdx.x >> 6;
#pragma unroll
  for (int i = 0; i < 16; ++i) {
    int b = y4 * 16 + i;
    tile[b][x] = in[(size_t)b * 131072 + (size_t)t * 1024 + k0 + x];
  }
  __syncthreads();
#pragma unroll
  for (int i = 0; i < 16; ++i) {
    int kk = y4 * 16 + i;
    inT[((size_t)t * 1024 + k0 + kk) * 64 + x] = tile[x][kk];
  }
}

// ---- init: fp64 master (normal) + fp32 transposed copies; barrier words ----
__global__ __launch_bounds__(256) void k_init(const float* __restrict__ memory,
                                              double* __restrict__ mem64,
                                              float* __restrict__ mem32T,
                                              float* __restrict__ tmem32T,
                                              unsigned* __restrict__ cnt,
                                              unsigned* __restrict__ gen, int n) {
  int i = blockIdx.x * 256 + threadIdx.x;
  if (i == 0) { *cnt = 0u; *gen = 0u; }
  if (i >= n) return;
  int m = i >> 10, c = i & 1023;
  double v = (double)memory[i];
  mem64[i] = v;
  mem32T[c * 192 + m] = (float)v;
  tmem32T[c * 192 + m] = (float)tanh(v);
}

// ---------------------------------------------------------------------------
// Persistent fused kernel. LDS (floats, column-major per slice):
// Wq 0 | Wk 4096 | Wv 8192 | Wo 12288 | W1 16384 | W2 20480 |
// Ug 24576 (8 cols) | Wg 32768 (8 cols) = 40960 floats = 160 KiB.
// Block bid owns square cols [4b,4b+4), wide cols [8b,8b+8).
// ---------------------------------------------------------------------------
__global__ __launch_bounds__(NTHR) void k_fused(
    const float* __restrict__ inputsT,
    const float* __restrict__ Wq, const float* __restrict__ Wk,
    const float* __restrict__ Wv, const float* __restrict__ Wo,
    const float* __restrict__ W1, const float* __restrict__ W2,
    const float* __restrict__ Wg, const float* __restrict__ Ug,
    const float* __restrict__ bq, const float* __restrict__ bk,
    const float* __restrict__ bv, const float* __restrict__ bo,
    const float* __restrict__ b1, const float* __restrict__ b2,
    const float* __restrict__ bg, const float* __restrict__ bu,
    double* __restrict__ mem64, double* __restrict__ nm64,
    float* __restrict__ mem32T, float* __restrict__ tmem32T,
    float* __restrict__ nm32T, float* __restrict__ o32T,
    float* __restrict__ h132T, float* __restrict__ q32,
    float* __restrict__ km32, float* __restrict__ vm32,
    float* __restrict__ g32, float* __restrict__ kx32,
    float* __restrict__ vx32, float* __restrict__ xg32,
    unsigned* __restrict__ cnt, unsigned* __restrict__ gen,
    float* __restrict__ out) {
  __shared__ float WL[40960];
  const int bid = blockIdx.x, tid = threadIdx.x;
  const int cq = bid * 4, cw = bid * 8;

  loadW(Wq, 1024, cq, 4, WL + 0);
  loadW(Wk, 1024, cq, 4, WL + 4096);
  loadW(Wv, 1024, cq, 4, WL + 8192);
  loadW(Wo, 1024, cq, 4, WL + 12288);
  loadW(W1, 1024, cq, 4, WL + 16384);
  loadW(W2, 1024, cq, 4, WL + 20480);
  loadW(Ug, 2048, cw, 8, WL + 24576);
  loadW(Wg, 2048, cw, 8, WL + 32768);
  __syncthreads();

  for (int t = 0; t < T_; ++t) {
    const float* inT = inputsT + (size_t)t * 65536;  // [k][b], ldr=64
    // ---------- phase A: 1216 4-col jobs ----------------------------------
    for (int j = tid; j < 1216; j += NTHR) {
      double a[4];
      if (j < 576) {                       // q/km/vm: (mat, row m)
        int mat = j / 192, m = j - mat * 192;
        dot4(mem32T, 192, m, WL + mat * 4096, a);
        float* dst = (mat == 0) ? q32 : (mat == 1) ? km32 : vm32;
        const float* bb = (mat == 0) ? bq : (mat == 1) ? bk : bv;
#pragma unroll
        for (int jj = 0; jj < 4; ++jj)
          dst[(size_t)m * 1024 + cq + jj] = (float)(a[jj] + (double)bb[cq + jj]);
      } else if (j < 960) {                // g = tanh(mem) @ Ug: (cg, row m)
        int r = j - 576, cg = r / 192, m = r - cg * 192;
        dot4(tmem32T, 192, m, WL + 24576 + cg * 4096, a);
#pragma unroll
        for (int jj = 0; jj < 4; ++jj)
          g32[(size_t)m * 2048 + cw + cg * 4 + jj] = (float)a[jj];
      } else if (j < 1088) {               // kx/vx: (mat, b)
        int r = j - 960, mat = r >> 6, b = r & 63;
        dot4(inT, 64, b, WL + (mat ? 8192 : 4096), a);
        float* dst = mat ? vx32 : kx32;
        const float* bb = mat ? bv : bk;
#pragma unroll
        for (int jj = 0; jj < 4; ++jj)
          dst[(size_t)b * 1024 + cq + jj] = (float)(a[jj] + (double)bb[cq + jj]);
      } else {                             // xg = x@Wg + bg + bu: (cg, b)
        int r = j - 1088, cg = r >> 6, b = r & 63;
        dot4(inT, 64, b, WL + 32768 + cg * 4096, a);
#pragma unroll
        for (int jj = 0; jj < 4; ++jj) {
          int c = cw + cg * 4 + jj;
          xg32[(size_t)b * 2048 + c] = (float)(a[jj] + (double)bg[c] + (double)bu[c]);
        }
      }
    }
    gsync(cnt, gen);

    // ---------- phase B: attention, 2 wave-jobs per block (512 total) ------
    {
      int wv = tid >> 6;
      if (wv < 2) {
        int bh = bid * 2 + wv;
        int b = bh >> 3, h = bh & 7, lane = tid & 63;
        int col = h * 128 + lane;
        double q0[3], q1[3], kk0[4], kk1[4], vv0[4], vv1[4];
#pragma unroll
        for (int s = 0; s < 3; ++s) {
          size_t r = (size_t)(b * 3 + s) * 1024 + col;
          q0[s] = (double)q32[r]; q1[s] = (double)q32[r + 64];
        }
#pragma unroll
        for (int j = 0; j < 3; ++j) {
          size_t r = (size_t)(b * 3 + j) * 1024 + col;
          kk0[j] = (double)km32[r]; kk1[j] = (double)km32[r + 64];
          vv0[j] = (double)vm32[r]; vv1[j] = (double)vm32[r + 64];
        }
        {
          size_t r = (size_t)b * 1024 + col;
          kk0[3] = (double)kx32[r]; kk1[3] = (double)kx32[r + 64];
          vv0[3] = (double)vx32[r]; vv1[3] = (double)vx32[r + 64];
        }
        const double scale = 0.08838834764831845;  // 1/sqrt(128)
        double p[3][4];
#pragma unroll
        for (int s = 0; s < 3; ++s)
#pragma unroll
          for (int j = 0; j < 4; ++j) {
            double d = q0[s] * kk0[j] + q1[s] * kk1[j];
#pragma unroll
            for (int off = 32; off > 0; off >>= 1) d += __shfl_xor(d, off);
            p[s][j] = d * scale;
          }
#pragma unroll
        for (int s = 0; s < 3; ++s) {
          double m = fmax(fmax(p[s][0], p[s][1]), fmax(p[s][2], p[s][3]));
          double e0 = exp(p[s][0] - m), e1 = exp(p[s][1] - m);
          double e2 = exp(p[s][2] - m), e3 = exp(p[s][3] - m);
          double inv = 1.0 / (e0 + e1 + e2 + e3);
          double o0 = (e0 * vv0[0] + e1 * vv0[1] + e2 * vv0[2] + e3 * vv0[3]) * inv;
          double o1 = (e0 * vv1[0] + e1 * vv1[1] + e2 * vv1[2] + e3 * vv1[3]) * inv;
          int m_ = b * 3 + s;
          o32T[(size_t)col * 192 + m_]        = (float)o0;
          o32T[(size_t)(col + 64) * 192 + m_] = (float)o1;
        }
      }
    }
    gsync(cnt, gen);

    // ---------- phase C: nm = mem + o@Wo + bo ------------------------------
    if (tid < 768) {
      int m = tid >> 2, jj = tid & 3, c = cq + jj;
      double acc = dot1(o32T, 192, m, WL + 12288 + jj * 1024);
      size_t id = (size_t)m * 1024 + c;
      double nv = mem64[id] + acc + (double)bo[c];
      nm64[id] = nv; nm32T[(size_t)c * 192 + m] = (float)nv;
    }
    gsync(cnt, gen);

    // ---------- phase D: h1 = relu(nm@W1 + b1) -----------------------------
    if (tid < 768) {
      int m = tid >> 2, jj = tid & 3, c = cq + jj;
      double acc = dot1(nm32T, 192, m, WL + 16384 + jj * 1024);
      h132T[(size_t)c * 192 + m] = (float)fmax(acc + (double)b1[c], 0.0);
    }
    gsync(cnt, gen);

    // ---------- phase E: ml = relu(h1@W2+b2); gate; state update; emit -----
    if (tid < 768) {
      int m = tid >> 2, jj = tid & 3, c = cq + jj;
      double acc = dot1(h132T, 192, m, WL + 20480 + jj * 1024);
      size_t id = (size_t)m * 1024 + c;
      double ml = fmax(acc + (double)b2[c], 0.0);
      double nm2 = nm64[id] + ml;
      int b = m / 3, s = m - b * 3;
      double ig = (double)xg32[(size_t)b * 2048 + c]        + (double)g32[(size_t)m * 2048 + c];
      double fg = (double)xg32[(size_t)b * 2048 + 1024 + c] + (double)g32[(size_t)m * 2048 + 1024 + c];
      double old = mem64[id];
      double nv = sigm_d(ig) * tanh(nm2) + sigm_d(fg) * old;
      out[(size_t)(b * T_ + t) * 3072 + s * 1024 + c] = (float)nv;
      mem64[id] = nv;
      mem32T[(size_t)c * 192 + m]  = (float)nv;
      tmem32T[(size_t)c * 192 + m] = (float)tanh(nv);
    }
    gsync(cnt, gen);
  }
}

// ---------------------------------------------------------------------------
extern "C" void kernel_launch(void* const* d_in, const int* in_sizes, int n_in,
                              void* d_out, int out_size, void* d_ws, size_t ws_size,
                              hipStream_t stream) {
  (void)in_sizes; (void)n_in; (void)out_size;
  const float* inputs = (const float*)d_in[0];
  const float* memory = (const float*)d_in[1];
  const float* Wq = (const float*)d_in[2];  const float* bq = (const float*)d_in[3];
  const float* Wk = (const float*)d_in[4];  const float* bk = (const float*)d_in[5];
  const float* Wv = (const float*)d_in[6];  const float* bv = (const float*)d_in[7];
  const float* Wo = (const float*)d_in[8];  const float* bo = (const float*)d_in[9];
  const float* W1 = (const float*)d_in[10]; const float* b1 = (const float*)d_in[11];
  const float* W2 = (const float*)d_in[12]; const float* b2 = (const float*)d_in[13];
  const float* Wg = (const float*)d_in[14]; const float* bg = (const float*)d_in[15];
  const float* Ug = (const float*)d_in[16]; const float* bu = (const float*)d_in[17];
  float* out = (float*)d_out;

  // Footprint ~45.6 MB (ws = 64 MiB). Bail-signature if wrong: absmax 4.3125.
  if (ws_size < (size_t)48 * 1024 * 1024) return;

  char* ws = (char*)d_ws;
  size_t off = 0;
  auto alloc = [&](size_t bytes) -> void* {
    void* p = ws + off; off += (bytes + 255) & ~(size_t)255; return p;
  };
  unsigned* cnt = (unsigned*)alloc(256);
  unsigned* gen = (unsigned*)alloc(256);
  float* inputsT = (float*)alloc((size_t)8388608 * 4);   // [t][k][b] 32MB
  double* mem64 = (double*)alloc((size_t)196608 * 8);
  double* nm64  = (double*)alloc((size_t)196608 * 8);
  float* mem32T  = (float*)alloc((size_t)196608 * 4);    // [c][m]
  float* tmem32T = (float*)alloc((size_t)196608 * 4);
  float* nm32T   = (float*)alloc((size_t)196608 * 4);
  float* o32T    = (float*)alloc((size_t)196608 * 4);
  float* h132T   = (float*)alloc((size_t)196608 * 4);
  float* q32     = (float*)alloc((size_t)196608 * 4);    // normal [m][c]
  float* km32    = (float*)alloc((size_t)196608 * 4);
  float* vm32    = (float*)alloc((size_t)196608 * 4);
  float* g32     = (float*)alloc((size_t)192 * 2048 * 4);
  float* kx32    = (float*)alloc((size_t)64 * 1024 * 4);
  float* vx32    = (float*)alloc((size_t)64 * 1024 * 4);
  float* xg32    = (float*)alloc((size_t)64 * 2048 * 4);

  k_trans<<<dim3(16, 128), 256, 0, stream>>>(inputs, inputsT);
  k_init<<<768, 256, 0, stream>>>(memory, mem64, mem32T, tmem32T, cnt, gen, 196608);
  k_fused<<<NBLK, NTHR, 0, stream>>>(inputsT, Wq, Wk, Wv, Wo, W1, W2, Wg, Ug,
                                     bq, bk, bv, bo, b1, b2, bg, bu,
                                     mem64, nm64, mem32T, tmem32T, nm32T, o32T,
                                     h132T, q32, km32, vm32, g32, kx32, vx32,
                                     xg32, cnt, gen, out);
}

// Round 15
// 54856.219 us; speedup vs baseline: 2.2577x; 2.2577x over previous
//
// R15: persistent + LDS-resident weights (R13 skeleton) with rebuilt compute:
//  - multi-col jobs: qkv 12-col, Ug 8-col, {kx/vx 8 + xg 8}, C/D/E 4-col
//    -> A float4 amortized over 12-48 FMAs, mem32 read 1x (was 3x)
//  - chunked-fp32 accumulation (32-k chunks flushed to fp64): no per-FMA cvt,
//    fp32 FMA rate. Calibrated on R5: predicted absmax ~0.03 << 0.086.
//  - W reads wave-uniform by construction (job-type blocks 64-aligned) ->
//    LDS broadcast, zero bank conflicts.
// Normal row-major activations, float4 loads (R14's scalar-load mistake undone).
#include <hip/hip_runtime.h>
#include <math.h>

#define T_ 128
#define NBLK 256
#define NTHR 1024

__device__ __forceinline__ double sigm_d(double x) { return 1.0 / (1.0 + exp(-x)); }

// ---- software grid barrier (R12/R13-proven) ----
__device__ __forceinline__ void gsync(unsigned* cnt, unsigned* gen) {
  __syncthreads();
  if (threadIdx.x == 0) {
    __threadfence();
    unsigned g = __hip_atomic_load(gen, __ATOMIC_RELAXED, __HIP_MEMORY_SCOPE_AGENT);
    unsigned a = __hip_atomic_fetch_add(cnt, 1u, __ATOMIC_ACQ_REL, __HIP_MEMORY_SCOPE_AGENT);
    if (a == NBLK - 1u) {
      __hip_atomic_store(cnt, 0u, __ATOMIC_RELAXED, __HIP_MEMORY_SCOPE_AGENT);
      __hip_atomic_store(gen, g + 1u, __ATOMIC_RELEASE, __HIP_MEMORY_SCOPE_AGENT);
    } else {
      while (__hip_atomic_load(gen, __ATOMIC_RELAXED, __HIP_MEMORY_SCOPE_AGENT) == g)
        __builtin_amdgcn_s_sleep(2);
      (void)__hip_atomic_load(gen, __ATOMIC_ACQUIRE, __HIP_MEMORY_SCOPE_AGENT);
    }
  }
  __syncthreads();
}

// ---- chunked-fp32 NC-col dot ----------------------------------------------
// A: fp32 row (global, contiguous, float4 loads). Wb: LDS, NC contiguous
// columns of 1024 floats (wave-uniform address -> broadcast). fp32 FMA into
// f[NC], flushed to fp64 acc[NC] every 32 k.
template<int NC>
__device__ __forceinline__ void dotc(const float* __restrict__ A,
                                     const float* __restrict__ Wb,
                                     double* __restrict__ acc) {
#pragma unroll
  for (int j = 0; j < NC; ++j) acc[j] = 0.0;
  for (int k0 = 0; k0 < 1024; k0 += 32) {
    float f[NC];
#pragma unroll
    for (int j = 0; j < NC; ++j) f[j] = 0.f;
#pragma unroll
    for (int k = 0; k < 32; k += 4) {
      float4 a = *(const float4*)(A + k0 + k);
#pragma unroll
      for (int j = 0; j < NC; ++j) {
        float4 w = *(const float4*)(Wb + j * 1024 + k0 + k);
        f[j] = fmaf(a.w, w.w, fmaf(a.z, w.z, fmaf(a.y, w.y, fmaf(a.x, w.x, f[j]))));
      }
    }
#pragma unroll
    for (int j = 0; j < NC; ++j) acc[j] += (double)f[j];
  }
}

// ---- stage W slice into LDS, column-major (no swizzle) ----
__device__ __forceinline__ void loadW(const float* __restrict__ G, int ldw,
                                      int col0, int ncol, float* __restrict__ dst) {
  for (int i = threadIdx.x; i < (ncol << 10); i += NTHR) {
    int j = i >> 10, k = i & 1023;
    dst[j * 1024 + k] = G[(size_t)k * ldw + col0 + j];
  }
}

// ---- init: fp64 master + fp32 copies (normal layout); barrier words ----
__global__ __launch_bounds__(256) void k_init(const float* __restrict__ memory,
                                              double* __restrict__ mem64,
                                              float* __restrict__ mem32,
                                              float* __restrict__ tmem32,
                                              unsigned* __restrict__ cnt,
                                              unsigned* __restrict__ gen, int n) {
  int i = blockIdx.x * 256 + threadIdx.x;
  if (i == 0) { *cnt = 0u; *gen = 0u; }
  if (i >= n) return;
  double v = (double)memory[i];
  mem64[i] = v; mem32[i] = (float)v; tmem32[i] = (float)tanh(v);
}

// ---------------------------------------------------------------------------
// Persistent fused kernel. LDS (floats, column-major per slice):
// Wq 0 | Wk 4096 | Wv 8192 | Wo 12288 | W1 16384 | W2 20480 |
// Ug 24576 (8 cols) | Wg 32768 (8 cols) = 40960 floats = 160 KiB.
// Block owns square cols [4b,4b+4), wide cols [8b,8b+8).
// Phase-A jobs (448): tid<192 qkv-12col | <384 Ug-8col | <448 {kv-8col,xg-8col}.
// Job-type boundaries are 64-aligned -> W addresses wave-uniform (broadcast).
// ---------------------------------------------------------------------------
__global__ __launch_bounds__(NTHR) void k_fused(
    const float* __restrict__ inputs,
    const float* __restrict__ Wq, const float* __restrict__ Wk,
    const float* __restrict__ Wv, const float* __restrict__ Wo,
    const float* __restrict__ W1, const float* __restrict__ W2,
    const float* __restrict__ Wg, const float* __restrict__ Ug,
    const float* __restrict__ bq, const float* __restrict__ bk,
    const float* __restrict__ bv, const float* __restrict__ bo,
    const float* __restrict__ b1, const float* __restrict__ b2,
    const float* __restrict__ bg, const float* __restrict__ bu,
    double* __restrict__ mem64, double* __restrict__ nm64,
    float* __restrict__ mem32, float* __restrict__ tmem32,
    float* __restrict__ nm32, float* __restrict__ o32,
    float* __restrict__ h132, float* __restrict__ q32,
    float* __restrict__ km32, float* __restrict__ vm32,
    float* __restrict__ g32, float* __restrict__ kx32,
    float* __restrict__ vx32, float* __restrict__ xg32,
    unsigned* __restrict__ cnt, unsigned* __restrict__ gen,
    float* __restrict__ out) {
  __shared__ float WL[40960];
  const int bid = blockIdx.x, tid = threadIdx.x;
  const int cq = bid * 4, cw = bid * 8;

  loadW(Wq, 1024, cq, 4, WL + 0);
  loadW(Wk, 1024, cq, 4, WL + 4096);
  loadW(Wv, 1024, cq, 4, WL + 8192);
  loadW(Wo, 1024, cq, 4, WL + 12288);
  loadW(W1, 1024, cq, 4, WL + 16384);
  loadW(W2, 1024, cq, 4, WL + 20480);
  loadW(Ug, 2048, cw, 8, WL + 24576);
  loadW(Wg, 2048, cw, 8, WL + 32768);
  __syncthreads();

  for (int t = 0; t < T_; ++t) {
    // ---------- phase A -----------------------------------------------------
    if (tid < 192) {                         // qkv: 12 cols (Wq|Wk|Wv slices)
      int m = tid;
      double a[12];
      dotc<12>(mem32 + (size_t)m * 1024, WL + 0, a);
#pragma unroll
      for (int j = 0; j < 4; ++j) {
        int c = cq + j; size_t r = (size_t)m * 1024 + c;
        q32 [r] = (float)(a[j]     + (double)bq[c]);
        km32[r] = (float)(a[4 + j] + (double)bk[c]);
        vm32[r] = (float)(a[8 + j] + (double)bv[c]);
      }
    } else if (tid < 384) {                  // g = tanh(mem) @ Ug: 8 cols
      int m = tid - 192;
      double a[8];
      dotc<8>(tmem32 + (size_t)m * 1024, WL + 24576, a);
#pragma unroll
      for (int j = 0; j < 8; ++j) g32[(size_t)m * 2048 + cw + j] = (float)a[j];
    } else if (tid < 448) {                  // kx/vx (8) + xg (8) for batch b
      int b = tid - 384;
      const float* Ax = inputs + ((size_t)b * T_ + t) * 1024;
      double a[8];
      dotc<8>(Ax, WL + 4096, a);             // Wk|Wv slices contiguous
#pragma unroll
      for (int j = 0; j < 4; ++j) {
        int c = cq + j;
        kx32[(size_t)b * 1024 + c] = (float)(a[j]     + (double)bk[c]);
        vx32[(size_t)b * 1024 + c] = (float)(a[4 + j] + (double)bv[c]);
      }
      double ag[8];
      dotc<8>(Ax, WL + 32768, ag);           // Wg slice
#pragma unroll
      for (int j = 0; j < 8; ++j) {
        int c = cw + j;
        xg32[(size_t)b * 2048 + c] = (float)(ag[j] + (double)bg[c] + (double)bu[c]);
      }
    }
    gsync(cnt, gen);

    // ---------- phase B: attention, 2 wave-jobs per block (512 total) ------
    {
      int wv = tid >> 6;
      if (wv < 2) {
        int bh = bid * 2 + wv;
        int b = bh >> 3, h = bh & 7, lane = tid & 63;
        int col = h * 128 + lane;
        double q0[3], q1[3], kk0[4], kk1[4], vv0[4], vv1[4];
#pragma unroll
        for (int s = 0; s < 3; ++s) {
          size_t r = (size_t)(b * 3 + s) * 1024 + col;
          q0[s] = (double)q32[r]; q1[s] = (double)q32[r + 64];
        }
#pragma unroll
        for (int j = 0; j < 3; ++j) {
          size_t r = (size_t)(b * 3 + j) * 1024 + col;
          kk0[j] = (double)km32[r]; kk1[j] = (double)km32[r + 64];
          vv0[j] = (double)vm32[r]; vv1[j] = (double)vm32[r + 64];
        }
        {
          size_t r = (size_t)b * 1024 + col;
          kk0[3] = (double)kx32[r]; kk1[3] = (double)kx32[r + 64];
          vv0[3] = (double)vx32[r]; vv1[3] = (double)vx32[r + 64];
        }
        const double scale = 0.08838834764831845;  // 1/sqrt(128)
        double p[3][4];
#pragma unroll
        for (int s = 0; s < 3; ++s)
#pragma unroll
          for (int j = 0; j < 4; ++j) {
            double d = q0[s] * kk0[j] + q1[s] * kk1[j];
#pragma unroll
            for (int off = 32; off > 0; off >>= 1) d += __shfl_xor(d, off);
            p[s][j] = d * scale;
          }
#pragma unroll
        for (int s = 0; s < 3; ++s) {
          double m = fmax(fmax(p[s][0], p[s][1]), fmax(p[s][2], p[s][3]));
          double e0 = exp(p[s][0] - m), e1 = exp(p[s][1] - m);
          double e2 = exp(p[s][2] - m), e3 = exp(p[s][3] - m);
          double inv = 1.0 / (e0 + e1 + e2 + e3);
          double o0 = (e0 * vv0[0] + e1 * vv0[1] + e2 * vv0[2] + e3 * vv0[3]) * inv;
          double o1 = (e0 * vv1[0] + e1 * vv1[1] + e2 * vv1[2] + e3 * vv1[3]) * inv;
          size_t r = (size_t)(b * 3 + s) * 1024 + col;
          o32[r] = (float)o0; o32[r + 64] = (float)o1;
        }
      }
    }
    gsync(cnt, gen);

    // ---------- phase C: nm = mem + o@Wo + bo ------------------------------
    if (tid < 192) {
      int m = tid;
      double a[4];
      dotc<4>(o32 + (size_t)m * 1024, WL + 12288, a);
#pragma unroll
      for (int j = 0; j < 4; ++j) {
        int c = cq + j; size_t id = (size_t)m * 1024 + c;
        double nv = mem64[id] + a[j] + (double)bo[c];
        nm64[id] = nv; nm32[id] = (float)nv;
      }
    }
    gsync(cnt, gen);

    // ---------- phase D: h1 = relu(nm@W1 + b1) -----------------------------
    if (tid < 192) {
      int m = tid;
      double a[4];
      dotc<4>(nm32 + (size_t)m * 1024, WL + 16384, a);
#pragma unroll
      for (int j = 0; j < 4; ++j) {
        int c = cq + j;
        h132[(size_t)m * 1024 + c] = (float)fmax(a[j] + (double)b1[c], 0.0);
      }
    }
    gsync(cnt, gen);

    // ---------- phase E: ml = relu(h1@W2+b2); gate; state update; emit -----
    if (tid < 192) {
      int m = tid;
      double a[4];
      dotc<4>(h132 + (size_t)m * 1024, WL + 20480, a);
      int b = m / 3, s = m - b * 3;
#pragma unroll
      for (int j = 0; j < 4; ++j) {
        int c = cq + j; size_t id = (size_t)m * 1024 + c;
        double ml = fmax(a[j] + (double)b2[c], 0.0);
        double nm2 = nm64[id] + ml;
        double ig = (double)xg32[(size_t)b * 2048 + c]        + (double)g32[(size_t)m * 2048 + c];
        double fg = (double)xg32[(size_t)b * 2048 + 1024 + c] + (double)g32[(size_t)m * 2048 + 1024 + c];
        double old = mem64[id];
        double nv = sigm_d(ig) * tanh(nm2) + sigm_d(fg) * old;
        out[(size_t)(b * T_ + t) * 3072 + s * 1024 + c] = (float)nv;
        mem64[id] = nv; mem32[id] = (float)nv; tmem32[id] = (float)tanh(nv);
      }
    }
    gsync(cnt, gen);
  }
}

// ---------------------------------------------------------------------------
extern "C" void kernel_launch(void* const* d_in, const int* in_sizes, int n_in,
                              void* d_out, int out_size, void* d_ws, size_t ws_size,
                              hipStream_t stream) {
  (void)in_sizes; (void)n_in; (void)out_size;
  const float* inputs = (const float*)d_in[0];
  const float* memory = (const float*)d_in[1];
  const float* Wq = (const float*)d_in[2];  const float* bq = (const float*)d_in[3];
  const float* Wk = (const float*)d_in[4];  const float* bk = (const float*)d_in[5];
  const float* Wv = (const float*)d_in[6];  const float* bv = (const float*)d_in[7];
  const float* Wo = (const float*)d_in[8];  const float* bo = (const float*)d_in[9];
  const float* W1 = (const float*)d_in[10]; const float* b1 = (const float*)d_in[11];
  const float* W2 = (const float*)d_in[12]; const float* b2 = (const float*)d_in[13];
  const float* Wg = (const float*)d_in[14]; const float* bg = (const float*)d_in[15];
  const float* Ug = (const float*)d_in[16]; const float* bu = (const float*)d_in[17];
  float* out = (float*)d_out;

  // Footprint ~11.6 MB (ws = 64 MiB). Bail-signature if wrong: absmax 4.3125.
  if (ws_size < (size_t)16 * 1024 * 1024) return;

  char* ws = (char*)d_ws;
  size_t off = 0;
  auto alloc = [&](size_t bytes) -> void* {
    void* p = ws + off; off += (bytes + 255) & ~(size_t)255; return p;
  };
  unsigned* cnt = (unsigned*)alloc(256);
  unsigned* gen = (unsigned*)alloc(256);
  double* mem64 = (double*)alloc((size_t)196608 * 8);
  double* nm64  = (double*)alloc((size_t)196608 * 8);
  float* mem32  = (float*)alloc((size_t)196608 * 4);
  float* tmem32 = (float*)alloc((size_t)196608 * 4);
  float* nm32   = (float*)alloc((size_t)196608 * 4);
  float* o32    = (float*)alloc((size_t)196608 * 4);
  float* h132   = (float*)alloc((size_t)196608 * 4);
  float* q32    = (float*)alloc((size_t)196608 * 4);
  float* km32   = (float*)alloc((size_t)196608 * 4);
  float* vm32   = (float*)alloc((size_t)196608 * 4);
  float* g32    = (float*)alloc((size_t)192 * 2048 * 4);
  float* kx32   = (float*)alloc((size_t)64 * 1024 * 4);
  float* vx32   = (float*)alloc((size_t)64 * 1024 * 4);
  float* xg32   = (float*)alloc((size_t)64 * 2048 * 4);

  k_init<<<768, 256, 0, stream>>>(memory, mem64, mem32, tmem32, cnt, gen, 196608);
  k_fused<<<NBLK, NTHR, 0, stream>>>(inputs, Wq, Wk, Wv, Wo, W1, W2, Wg, Ug,
                                     bq, bk, bv, bo, b1, b2, bg, bu,
                                     mem64, nm64, mem32, tmem32, nm32, o32,
                                     h132, q32, km32, vm32, g32, kx32, vx32,
                                     xg32, cnt, gen, out);
}

// Round 16
// 36863.925 us; speedup vs baseline: 3.3596x; 1.4881x over previous
//
// R16: R15 skeleton (persistent, 160KB LDS-resident weights, broadcast W
// reads, chunked-fp32 + fp64 flush, R12 gsync) with FULL-OCCUPANCY phases:
//  - phase A: 1024 lanes exactly -- lane pairs split k (kh=tid&1, 512 each);
//    waves 0-5 qkv(12col), 6-11 Ug(8col), 12-13 kx/vx(8col), 14-15 xg(8col);
//    combine = v + __shfl_xor(v,1) (commutative -> deterministic).
//  - phases C/D/E: 768 lanes (12 waves), 4-way split-k (256 k each),
//    butterfly xor1/xor2 reduce, kq==0 writes.
// R15 failure mode fixed: 192-448 active threads -> 1 wave/SIMD latency
// exposure (VALUBusy 17.6%). Now every SIMD holds 3-4 active waves.
#include <hip/hip_runtime.h>
#include <math.h>

#define T_ 128
#define NBLK 256
#define NTHR 1024

__device__ __forceinline__ double sigm_d(double x) { return 1.0 / (1.0 + exp(-x)); }

// ---- software grid barrier (R12/R13-proven) ----
__device__ __forceinline__ void gsync(unsigned* cnt, unsigned* gen) {
  __syncthreads();
  if (threadIdx.x == 0) {
    __threadfence();
    unsigned g = __hip_atomic_load(gen, __ATOMIC_RELAXED, __HIP_MEMORY_SCOPE_AGENT);
    unsigned a = __hip_atomic_fetch_add(cnt, 1u, __ATOMIC_ACQ_REL, __HIP_MEMORY_SCOPE_AGENT);
    if (a == NBLK - 1u) {
      __hip_atomic_store(cnt, 0u, __ATOMIC_RELAXED, __HIP_MEMORY_SCOPE_AGENT);
      __hip_atomic_store(gen, g + 1u, __ATOMIC_RELEASE, __HIP_MEMORY_SCOPE_AGENT);
    } else {
      while (__hip_atomic_load(gen, __ATOMIC_RELAXED, __HIP_MEMORY_SCOPE_AGENT) == g)
        __builtin_amdgcn_s_sleep(2);
      (void)__hip_atomic_load(gen, __ATOMIC_ACQUIRE, __HIP_MEMORY_SCOPE_AGENT);
    }
  }
  __syncthreads();
}

// ---- chunked-fp32 NC-col partial dot over KLEN ks -------------------------
// A: fp32 (global), KLEN contiguous. Wb: LDS base already offset to k-start;
// column stride 1024 floats. fp32 FMA, flushed to fp64 every 32 k.
template<int NC, int KLEN>
__device__ __forceinline__ void dotc(const float* __restrict__ A,
                                     const float* __restrict__ Wb,
                                     double* __restrict__ acc) {
#pragma unroll
  for (int j = 0; j < NC; ++j) acc[j] = 0.0;
  for (int k0 = 0; k0 < KLEN; k0 += 32) {
    float f[NC];
#pragma unroll
    for (int j = 0; j < NC; ++j) f[j] = 0.f;
#pragma unroll
    for (int k = 0; k < 32; k += 4) {
      float4 a = *(const float4*)(A + k0 + k);
#pragma unroll
      for (int j = 0; j < NC; ++j) {
        float4 w = *(const float4*)(Wb + j * 1024 + k0 + k);
        f[j] = fmaf(a.w, w.w, fmaf(a.z, w.z, fmaf(a.y, w.y, fmaf(a.x, w.x, f[j]))));
      }
    }
#pragma unroll
    for (int j = 0; j < NC; ++j) acc[j] += (double)f[j];
  }
}

__device__ __forceinline__ double red2(double v) { return v + __shfl_xor(v, 1); }
__device__ __forceinline__ double red4(double v) {
  double s = v + __shfl_xor(v, 1);
  return s + __shfl_xor(s, 2);
}

// ---- stage W slice into LDS, column-major ----
__device__ __forceinline__ void loadW(const float* __restrict__ G, int ldw,
                                      int col0, int ncol, float* __restrict__ dst) {
  for (int i = threadIdx.x; i < (ncol << 10); i += NTHR) {
    int j = i >> 10, k = i & 1023;
    dst[j * 1024 + k] = G[(size_t)k * ldw + col0 + j];
  }
}

// ---- init ----
__global__ __launch_bounds__(256) void k_init(const float* __restrict__ memory,
                                              double* __restrict__ mem64,
                                              float* __restrict__ mem32,
                                              float* __restrict__ tmem32,
                                              unsigned* __restrict__ cnt,
                                              unsigned* __restrict__ gen, int n) {
  int i = blockIdx.x * 256 + threadIdx.x;
  if (i == 0) { *cnt = 0u; *gen = 0u; }
  if (i >= n) return;
  double v = (double)memory[i];
  mem64[i] = v; mem32[i] = (float)v; tmem32[i] = (float)tanh(v);
}

// ---------------------------------------------------------------------------
// LDS: Wq 0 | Wk 4096 | Wv 8192 | Wo 12288 | W1 16384 | W2 20480 |
//      Ug 24576 (8c) | Wg 32768 (8c) = 160 KiB.
// Block owns square cols [4b,4b+4), wide cols [8b,8b+8).
// ---------------------------------------------------------------------------
__global__ __launch_bounds__(NTHR) void k_fused(
    const float* __restrict__ inputs,
    const float* __restrict__ Wq, const float* __restrict__ Wk,
    const float* __restrict__ Wv, const float* __restrict__ Wo,
    const float* __restrict__ W1, const float* __restrict__ W2,
    const float* __restrict__ Wg, const float* __restrict__ Ug,
    const float* __restrict__ bq, const float* __restrict__ bk,
    const float* __restrict__ bv, const float* __restrict__ bo,
    const float* __restrict__ b1, const float* __restrict__ b2,
    const float* __restrict__ bg, const float* __restrict__ bu,
    double* __restrict__ mem64, double* __restrict__ nm64,
    float* __restrict__ mem32, float* __restrict__ tmem32,
    float* __restrict__ nm32, float* __restrict__ o32,
    float* __restrict__ h132, float* __restrict__ q32,
    float* __restrict__ km32, float* __restrict__ vm32,
    float* __restrict__ g32, float* __restrict__ kx32,
    float* __restrict__ vx32, float* __restrict__ xg32,
    unsigned* __restrict__ cnt, unsigned* __restrict__ gen,
    float* __restrict__ out) {
  __shared__ float WL[40960];
  const int bid = blockIdx.x, tid = threadIdx.x;
  const int cq = bid * 4, cw = bid * 8;

  loadW(Wq, 1024, cq, 4, WL + 0);
  loadW(Wk, 1024, cq, 4, WL + 4096);
  loadW(Wv, 1024, cq, 4, WL + 8192);
  loadW(Wo, 1024, cq, 4, WL + 12288);
  loadW(W1, 1024, cq, 4, WL + 16384);
  loadW(W2, 1024, cq, 4, WL + 20480);
  loadW(Ug, 2048, cw, 8, WL + 24576);
  loadW(Wg, 2048, cw, 8, WL + 32768);
  __syncthreads();

  for (int t = 0; t < T_; ++t) {
    // ---------- phase A: all 16 waves, lane-pair split-k (kh = tid&1) -------
    {
      const int kh = tid & 1, ko = kh << 9;           // 0 or 512
      if (tid < 384) {                                // qkv, 12 cols
        int m = tid >> 1;
        double a[12];
        dotc<12, 512>(mem32 + (size_t)m * 1024 + ko, WL + ko, a);
#pragma unroll
        for (int j = 0; j < 12; ++j) a[j] = red2(a[j]);
        if (!kh) {
#pragma unroll
          for (int j = 0; j < 4; ++j) {
            int c = cq + j; size_t r = (size_t)m * 1024 + c;
            q32 [r] = (float)(a[j]     + (double)bq[c]);
            km32[r] = (float)(a[4 + j] + (double)bk[c]);
            vm32[r] = (float)(a[8 + j] + (double)bv[c]);
          }
        }
      } else if (tid < 768) {                         // Ug, 8 cols
        int m = (tid - 384) >> 1;
        double a[8];
        dotc<8, 512>(tmem32 + (size_t)m * 1024 + ko, WL + 24576 + ko, a);
#pragma unroll
        for (int j = 0; j < 8; ++j) a[j] = red2(a[j]);
        if (!kh)
#pragma unroll
          for (int j = 0; j < 8; ++j) g32[(size_t)m * 2048 + cw + j] = (float)a[j];
      } else if (tid < 896) {                         // kx/vx, 8 cols (Wk|Wv)
        int b = (tid - 768) >> 1;
        double a[8];
        dotc<8, 512>(inputs + ((size_t)b * T_ + t) * 1024 + ko, WL + 4096 + ko, a);
#pragma unroll
        for (int j = 0; j < 8; ++j) a[j] = red2(a[j]);
        if (!kh) {
#pragma unroll
          for (int j = 0; j < 4; ++j) {
            int c = cq + j;
            kx32[(size_t)b * 1024 + c] = (float)(a[j]     + (double)bk[c]);
            vx32[(size_t)b * 1024 + c] = (float)(a[4 + j] + (double)bv[c]);
          }
        }
      } else {                                        // xg, 8 cols (Wg)
        int b = (tid - 896) >> 1;
        double a[8];
        dotc<8, 512>(inputs + ((size_t)b * T_ + t) * 1024 + ko, WL + 32768 + ko, a);
#pragma unroll
        for (int j = 0; j < 8; ++j) a[j] = red2(a[j]);
        if (!kh)
#pragma unroll
          for (int j = 0; j < 8; ++j) {
            int c = cw + j;
            xg32[(size_t)b * 2048 + c] = (float)(a[j] + (double)bg[c] + (double)bu[c]);
          }
      }
    }
    gsync(cnt, gen);

    // ---------- phase B: attention, 2 wave-jobs per block (512 total) ------
    {
      int wv = tid >> 6;
      if (wv < 2) {
        int bh = bid * 2 + wv;
        int b = bh >> 3, h = bh & 7, lane = tid & 63;
        int col = h * 128 + lane;
        double q0[3], q1[3], kk0[4], kk1[4], vv0[4], vv1[4];
#pragma unroll
        for (int s = 0; s < 3; ++s) {
          size_t r = (size_t)(b * 3 + s) * 1024 + col;
          q0[s] = (double)q32[r]; q1[s] = (double)q32[r + 64];
        }
#pragma unroll
        for (int j = 0; j < 3; ++j) {
          size_t r = (size_t)(b * 3 + j) * 1024 + col;
          kk0[j] = (double)km32[r]; kk1[j] = (double)km32[r + 64];
          vv0[j] = (double)vm32[r]; vv1[j] = (double)vm32[r + 64];
        }
        {
          size_t r = (size_t)b * 1024 + col;
          kk0[3] = (double)kx32[r]; kk1[3] = (double)kx32[r + 64];
          vv0[3] = (double)vx32[r]; vv1[3] = (double)vx32[r + 64];
        }
        const double scale = 0.08838834764831845;  // 1/sqrt(128)
        double p[3][4];
#pragma unroll
        for (int s = 0; s < 3; ++s)
#pragma unroll
          for (int j = 0; j < 4; ++j) {
            double d = q0[s] * kk0[j] + q1[s] * kk1[j];
#pragma unroll
            for (int off = 32; off > 0; off >>= 1) d += __shfl_xor(d, off);
            p[s][j] = d * scale;
          }
#pragma unroll
        for (int s = 0; s < 3; ++s) {
          double m = fmax(fmax(p[s][0], p[s][1]), fmax(p[s][2], p[s][3]));
          double e0 = exp(p[s][0] - m), e1 = exp(p[s][1] - m);
          double e2 = exp(p[s][2] - m), e3 = exp(p[s][3] - m);
          double inv = 1.0 / (e0 + e1 + e2 + e3);
          double o0 = (e0 * vv0[0] + e1 * vv0[1] + e2 * vv0[2] + e3 * vv0[3]) * inv;
          double o1 = (e0 * vv1[0] + e1 * vv1[1] + e2 * vv1[2] + e3 * vv1[3]) * inv;
          size_t r = (size_t)(b * 3 + s) * 1024 + col;
          o32[r] = (float)o0; o32[r + 64] = (float)o1;
        }
      }
    }
    gsync(cnt, gen);

    // ---------- phase C: nm = mem + o@Wo + bo  (12 waves, 4-way split-k) ---
    if (tid < 768) {
      int m = tid >> 2, kq = tid & 3, ko = kq << 8;   // 256-k quarter
      double a[4];
      dotc<4, 256>(o32 + (size_t)m * 1024 + ko, WL + 12288 + ko, a);
#pragma unroll
      for (int j = 0; j < 4; ++j) a[j] = red4(a[j]);
      if (!kq) {
#pragma unroll
        for (int j = 0; j < 4; ++j) {
          int c = cq + j; size_t id = (size_t)m * 1024 + c;
          double nv = mem64[id] + a[j] + (double)bo[c];
          nm64[id] = nv; nm32[id] = (float)nv;
        }
      }
    }
    gsync(cnt, gen);

    // ---------- phase D: h1 = relu(nm@W1 + b1) -----------------------------
    if (tid < 768) {
      int m = tid >> 2, kq = tid & 3, ko = kq << 8;
      double a[4];
      dotc<4, 256>(nm32 + (size_t)m * 1024 + ko, WL + 16384 + ko, a);
#pragma unroll
      for (int j = 0; j < 4; ++j) a[j] = red4(a[j]);
      if (!kq) {
#pragma unroll
        for (int j = 0; j < 4; ++j) {
          int c = cq + j;
          h132[(size_t)m * 1024 + c] = (float)fmax(a[j] + (double)b1[c], 0.0);
        }
      }
    }
    gsync(cnt, gen);

    // ---------- phase E: ml = relu(h1@W2+b2); gate; update; emit -----------
    if (tid < 768) {
      int m = tid >> 2, kq = tid & 3, ko = kq << 8;
      double a[4];
      dotc<4, 256>(h132 + (size_t)m * 1024 + ko, WL + 20480 + ko, a);
#pragma unroll
      for (int j = 0; j < 4; ++j) a[j] = red4(a[j]);
      if (!kq) {
        int b = m / 3, s = m - b * 3;
#pragma unroll
        for (int j = 0; j < 4; ++j) {
          int c = cq + j; size_t id = (size_t)m * 1024 + c;
          double ml = fmax(a[j] + (double)b2[c], 0.0);
          double nm2 = nm64[id] + ml;
          double ig = (double)xg32[(size_t)b * 2048 + c]        + (double)g32[(size_t)m * 2048 + c];
          double fg = (double)xg32[(size_t)b * 2048 + 1024 + c] + (double)g32[(size_t)m * 2048 + 1024 + c];
          double old = mem64[id];
          double nv = sigm_d(ig) * tanh(nm2) + sigm_d(fg) * old;
          out[(size_t)(b * T_ + t) * 3072 + s * 1024 + c] = (float)nv;
          mem64[id] = nv; mem32[id] = (float)nv; tmem32[id] = (float)tanh(nv);
        }
      }
    }
    gsync(cnt, gen);
  }
}

// ---------------------------------------------------------------------------
extern "C" void kernel_launch(void* const* d_in, const int* in_sizes, int n_in,
                              void* d_out, int out_size, void* d_ws, size_t ws_size,
                              hipStream_t stream) {
  (void)in_sizes; (void)n_in; (void)out_size;
  const float* inputs = (const float*)d_in[0];
  const float* memory = (const float*)d_in[1];
  const float* Wq = (const float*)d_in[2];  const float* bq = (const float*)d_in[3];
  const float* Wk = (const float*)d_in[4];  const float* bk = (const float*)d_in[5];
  const float* Wv = (const float*)d_in[6];  const float* bv = (const float*)d_in[7];
  const float* Wo = (const float*)d_in[8];  const float* bo = (const float*)d_in[9];
  const float* W1 = (const float*)d_in[10]; const float* b1 = (const float*)d_in[11];
  const float* W2 = (const float*)d_in[12]; const float* b2 = (const float*)d_in[13];
  const float* Wg = (const float*)d_in[14]; const float* bg = (const float*)d_in[15];
  const float* Ug = (const float*)d_in[16]; const float* bu = (const float*)d_in[17];
  float* out = (float*)d_out;

  if (ws_size < (size_t)16 * 1024 * 1024) return;

  char* ws = (char*)d_ws;
  size_t off = 0;
  auto alloc = [&](size_t bytes) -> void* {
    void* p = ws + off; off += (bytes + 255) & ~(size_t)255; return p;
  };
  unsigned* cnt = (unsigned*)alloc(256);
  unsigned* gen = (unsigned*)alloc(256);
  double* mem64 = (double*)alloc((size_t)196608 * 8);
  double* nm64  = (double*)alloc((size_t)196608 * 8);
  float* mem32  = (float*)alloc((size_t)196608 * 4);
  float* tmem32 = (float*)alloc((size_t)196608 * 4);
  float* nm32   = (float*)alloc((size_t)196608 * 4);
  float* o32    = (float*)alloc((size_t)196608 * 4);
  float* h132   = (float*)alloc((size_t)196608 * 4);
  float* q32    = (float*)alloc((size_t)196608 * 4);
  float* km32   = (float*)alloc((size_t)196608 * 4);
  float* vm32   = (float*)alloc((size_t)196608 * 4);
  float* g32    = (float*)alloc((size_t)192 * 2048 * 4);
  float* kx32   = (float*)alloc((size_t)64 * 1024 * 4);
  float* vx32   = (float*)alloc((size_t)64 * 1024 * 4);
  float* xg32   = (float*)alloc((size_t)64 * 2048 * 4);

  k_init<<<768, 256, 0, stream>>>(memory, mem64, mem32, tmem32, cnt, gen, 196608);
  k_fused<<<NBLK, NTHR, 0, stream>>>(inputs, Wq, Wk, Wv, Wo, W1, W2, Wg, Ug,
                                     bq, bk, bv, bo, b1, b2, bg, bu,
                                     mem64, nm64, mem32, tmem32, nm32, o32,
                                     h132, q32, km32, vm32, g32, kx32, vx32,
                                     xg32, cnt, gen, out);
}

// Round 17
// 32330.963 us; speedup vs baseline: 3.8306x; 1.1402x over previous
//
// R17: R16 + LDS bank-conflict elimination (the 8.58e9-conflict fix):
//  - W columns stored with quarter-XOR swizzle: float k of a column lives at
//    (k & ~255) | ((k&255) ^ ((k>>8 & 3)<<3)). The four 256-k quarters map to
//    bank groups rotated by 0/8/16/24 -> all split-k reads bank-disjoint.
//    Footprint unchanged: exactly 40960 floats = 160 KiB.
//  - phase A split-k moved to half-wave granularity (kh = lane>>5, combine
//    via __shfl_xor(v,32)): uniform W address per half-wave (broadcast).
//  - C/D/E unchanged (kq=tid&3); swizzle makes their 4 addresses disjoint.
// Summation order identical to R16 -> absmax stays exactly 0.015625.
#include <hip/hip_runtime.h>
#include <math.h>

#define T_ 128
#define NBLK 256
#define NTHR 1024

__device__ __forceinline__ double sigm_d(double x) { return 1.0 / (1.0 + exp(-x)); }

// ---- software grid barrier (R12/R13-proven) ----
__device__ __forceinline__ void gsync(unsigned* cnt, unsigned* gen) {
  __syncthreads();
  if (threadIdx.x == 0) {
    __threadfence();
    unsigned g = __hip_atomic_load(gen, __ATOMIC_RELAXED, __HIP_MEMORY_SCOPE_AGENT);
    unsigned a = __hip_atomic_fetch_add(cnt, 1u, __ATOMIC_ACQ_REL, __HIP_MEMORY_SCOPE_AGENT);
    if (a == NBLK - 1u) {
      __hip_atomic_store(cnt, 0u, __ATOMIC_RELAXED, __HIP_MEMORY_SCOPE_AGENT);
      __hip_atomic_store(gen, g + 1u, __ATOMIC_RELEASE, __HIP_MEMORY_SCOPE_AGENT);
    } else {
      while (__hip_atomic_load(gen, __ATOMIC_RELAXED, __HIP_MEMORY_SCOPE_AGENT) == g)
        __builtin_amdgcn_s_sleep(2);
      (void)__hip_atomic_load(gen, __ATOMIC_ACQUIRE, __HIP_MEMORY_SCOPE_AGENT);
    }
  }
  __syncthreads();
}

// ---- chunked-fp32 NC-col partial dot over KLEN ks, quarter-swizzled W ------
// A: fp32 (global), already offset to kstart. Wb: LDS slice base (col stride
// 1024 floats, quarter-XOR layout). kstart: global k offset (multiple of 256,
// or 512). fp32 FMA, flushed to fp64 every 32 k. Ascending-k order.
template<int NC, int KLEN>
__device__ __forceinline__ void dotc(const float* __restrict__ A,
                                     const float* __restrict__ Wb,
                                     int kstart, double* __restrict__ acc) {
#pragma unroll
  for (int j = 0; j < NC; ++j) acc[j] = 0.0;
#pragma unroll
  for (int q0 = 0; q0 < KLEN; q0 += 256) {
    const int rot = (((kstart + q0) >> 8) & 3) << 3;
    const float* Wq = Wb + kstart + q0;
    const float* Aq = A + q0;
#pragma unroll
    for (int k0 = 0; k0 < 256; k0 += 32) {
      float f[NC];
#pragma unroll
      for (int j = 0; j < NC; ++j) f[j] = 0.f;
#pragma unroll
      for (int k = 0; k < 32; k += 4) {
        float4 a = *(const float4*)(Aq + k0 + k);
#pragma unroll
        for (int j = 0; j < NC; ++j) {
          float4 w = *(const float4*)(Wq + j * 1024 + ((k0 + k) ^ rot));
          f[j] = fmaf(a.w, w.w, fmaf(a.z, w.z, fmaf(a.y, w.y, fmaf(a.x, w.x, f[j]))));
        }
      }
#pragma unroll
      for (int j = 0; j < NC; ++j) acc[j] += (double)f[j];
    }
  }
}

__device__ __forceinline__ double red32(double v) { return v + __shfl_xor(v, 32); }
__device__ __forceinline__ double red4(double v) {
  double s = v + __shfl_xor(v, 1);
  return s + __shfl_xor(s, 2);
}

// ---- stage W slice into LDS, column-major with quarter-XOR swizzle ----
__device__ __forceinline__ void loadW(const float* __restrict__ G, int ldw,
                                      int col0, int ncol, float* __restrict__ dst) {
  for (int i = threadIdx.x; i < (ncol << 10); i += NTHR) {
    int j = i >> 10, k = i & 1023;
    int pos = (k & ~255) | ((k & 255) ^ (((k >> 8) & 3) << 3));
    dst[j * 1024 + pos] = G[(size_t)k * ldw + col0 + j];
  }
}

// ---- init ----
__global__ __launch_bounds__(256) void k_init(const float* __restrict__ memory,
                                              double* __restrict__ mem64,
                                              float* __restrict__ mem32,
                                              float* __restrict__ tmem32,
                                              unsigned* __restrict__ cnt,
                                              unsigned* __restrict__ gen, int n) {
  int i = blockIdx.x * 256 + threadIdx.x;
  if (i == 0) { *cnt = 0u; *gen = 0u; }
  if (i >= n) return;
  double v = (double)memory[i];
  mem64[i] = v; mem32[i] = (float)v; tmem32[i] = (float)tanh(v);
}

// ---------------------------------------------------------------------------
// LDS: Wq 0 | Wk 4096 | Wv 8192 | Wo 12288 | W1 16384 | W2 20480 |
//      Ug 24576 (8c) | Wg 32768 (8c) = 160 KiB.  Block owns square cols
//      [4b,4b+4), wide cols [8b,8b+8).
// Phase A (16 waves): w0-5 qkv (m=w*32+lane&31, 12col) | w6-11 Ug (8col) |
//   w12-13 kx/vx | w14-15 xg.  kh = lane>>5 (512-k halves).
// ---------------------------------------------------------------------------
__global__ __launch_bounds__(NTHR) void k_fused(
    const float* __restrict__ inputs,
    const float* __restrict__ Wq, const float* __restrict__ Wk,
    const float* __restrict__ Wv, const float* __restrict__ Wo,
    const float* __restrict__ W1, const float* __restrict__ W2,
    const float* __restrict__ Wg, const float* __restrict__ Ug,
    const float* __restrict__ bq, const float* __restrict__ bk,
    const float* __restrict__ bv, const float* __restrict__ bo,
    const float* __restrict__ b1, const float* __restrict__ b2,
    const float* __restrict__ bg, const float* __restrict__ bu,
    double* __restrict__ mem64, double* __restrict__ nm64,
    float* __restrict__ mem32, float* __restrict__ tmem32,
    float* __restrict__ nm32, float* __restrict__ o32,
    float* __restrict__ h132, float* __restrict__ q32,
    float* __restrict__ km32, float* __restrict__ vm32,
    float* __restrict__ g32, float* __restrict__ kx32,
    float* __restrict__ vx32, float* __restrict__ xg32,
    unsigned* __restrict__ cnt, unsigned* __restrict__ gen,
    float* __restrict__ out) {
  __shared__ float WL[40960];
  const int bid = blockIdx.x, tid = threadIdx.x;
  const int cq = bid * 4, cw = bid * 8;
  const int wv = tid >> 6, lane = tid & 63;

  loadW(Wq, 1024, cq, 4, WL + 0);
  loadW(Wk, 1024, cq, 4, WL + 4096);
  loadW(Wv, 1024, cq, 4, WL + 8192);
  loadW(Wo, 1024, cq, 4, WL + 12288);
  loadW(W1, 1024, cq, 4, WL + 16384);
  loadW(W2, 1024, cq, 4, WL + 20480);
  loadW(Ug, 2048, cw, 8, WL + 24576);
  loadW(Wg, 2048, cw, 8, WL + 32768);
  __syncthreads();

  for (int t = 0; t < T_; ++t) {
    // ---------- phase A: 16 waves, half-wave split-k (kh = lane>>5) --------
    {
      const int kh = lane >> 5, ko = kh << 9;        // 0 or 512
      const int sub = lane & 31;
      if (wv < 6) {                                  // qkv, 12 cols
        int m = wv * 32 + sub;
        double a[12];
        dotc<12, 512>(mem32 + (size_t)m * 1024 + ko, WL + 0, ko, a);
#pragma unroll
        for (int j = 0; j < 12; ++j) a[j] = red32(a[j]);
        if (!kh) {
#pragma unroll
          for (int j = 0; j < 4; ++j) {
            int c = cq + j; size_t r = (size_t)m * 1024 + c;
            q32 [r] = (float)(a[j]     + (double)bq[c]);
            km32[r] = (float)(a[4 + j] + (double)bk[c]);
            vm32[r] = (float)(a[8 + j] + (double)bv[c]);
          }
        }
      } else if (wv < 12) {                          // Ug, 8 cols
        int m = (wv - 6) * 32 + sub;
        double a[8];
        dotc<8, 512>(tmem32 + (size_t)m * 1024 + ko, WL + 24576, ko, a);
#pragma unroll
        for (int j = 0; j < 8; ++j) a[j] = red32(a[j]);
        if (!kh)
#pragma unroll
          for (int j = 0; j < 8; ++j) g32[(size_t)m * 2048 + cw + j] = (float)a[j];
      } else if (wv < 14) {                          // kx/vx, 8 cols (Wk|Wv)
        int b = (wv - 12) * 32 + sub;
        double a[8];
        dotc<8, 512>(inputs + ((size_t)b * T_ + t) * 1024 + ko, WL + 4096, ko, a);
#pragma unroll
        for (int j = 0; j < 8; ++j) a[j] = red32(a[j]);
        if (!kh) {
#pragma unroll
          for (int j = 0; j < 4; ++j) {
            int c = cq + j;
            kx32[(size_t)b * 1024 + c] = (float)(a[j]     + (double)bk[c]);
            vx32[(size_t)b * 1024 + c] = (float)(a[4 + j] + (double)bv[c]);
          }
        }
      } else {                                       // xg, 8 cols (Wg)
        int b = (wv - 14) * 32 + sub;
        double a[8];
        dotc<8, 512>(inputs + ((size_t)b * T_ + t) * 1024 + ko, WL + 32768, ko, a);
#pragma unroll
        for (int j = 0; j < 8; ++j) a[j] = red32(a[j]);
        if (!kh)
#pragma unroll
          for (int j = 0; j < 8; ++j) {
            int c = cw + j;
            xg32[(size_t)b * 2048 + c] = (float)(a[j] + (double)bg[c] + (double)bu[c]);
          }
      }
    }
    gsync(cnt, gen);

    // ---------- phase B: attention, 2 wave-jobs per block (512 total) ------
    if (wv < 2) {
      int bh = bid * 2 + wv;
      int b = bh >> 3, h = bh & 7;
      int col = h * 128 + lane;
      double q0[3], q1[3], kk0[4], kk1[4], vv0[4], vv1[4];
#pragma unroll
      for (int s = 0; s < 3; ++s) {
        size_t r = (size_t)(b * 3 + s) * 1024 + col;
        q0[s] = (double)q32[r]; q1[s] = (double)q32[r + 64];
      }
#pragma unroll
      for (int j = 0; j < 3; ++j) {
        size_t r = (size_t)(b * 3 + j) * 1024 + col;
        kk0[j] = (double)km32[r]; kk1[j] = (double)km32[r + 64];
        vv0[j] = (double)vm32[r]; vv1[j] = (double)vm32[r + 64];
      }
      {
        size_t r = (size_t)b * 1024 + col;
        kk0[3] = (double)kx32[r]; kk1[3] = (double)kx32[r + 64];
        vv0[3] = (double)vx32[r]; vv1[3] = (double)vx32[r + 64];
      }
      const double scale = 0.08838834764831845;  // 1/sqrt(128)
      double p[3][4];
#pragma unroll
      for (int s = 0; s < 3; ++s)
#pragma unroll
        for (int j = 0; j < 4; ++j) {
          double d = q0[s] * kk0[j] + q1[s] * kk1[j];
#pragma unroll
          for (int off = 32; off > 0; off >>= 1) d += __shfl_xor(d, off);
          p[s][j] = d * scale;
        }
#pragma unroll
      for (int s = 0; s < 3; ++s) {
        double m = fmax(fmax(p[s][0], p[s][1]), fmax(p[s][2], p[s][3]));
        double e0 = exp(p[s][0] - m), e1 = exp(p[s][1] - m);
        double e2 = exp(p[s][2] - m), e3 = exp(p[s][3] - m);
        double inv = 1.0 / (e0 + e1 + e2 + e3);
        double o0 = (e0 * vv0[0] + e1 * vv0[1] + e2 * vv0[2] + e3 * vv0[3]) * inv;
        double o1 = (e0 * vv1[0] + e1 * vv1[1] + e2 * vv1[2] + e3 * vv1[3]) * inv;
        size_t r = (size_t)(b * 3 + s) * 1024 + col;
        o32[r] = (float)o0; o32[r + 64] = (float)o1;
      }
    }
    gsync(cnt, gen);

    // ---------- phase C: nm = mem + o@Wo + bo  (12 waves, 4-way split-k) ---
    if (tid < 768) {
      int m = tid >> 2, kq = tid & 3, ko = kq << 8;
      double a[4];
      dotc<4, 256>(o32 + (size_t)m * 1024 + ko, WL + 12288, ko, a);
#pragma unroll
      for (int j = 0; j < 4; ++j) a[j] = red4(a[j]);
      if (!kq) {
#pragma unroll
        for (int j = 0; j < 4; ++j) {
          int c = cq + j; size_t id = (size_t)m * 1024 + c;
          double nv = mem64[id] + a[j] + (double)bo[c];
          nm64[id] = nv; nm32[id] = (float)nv;
        }
      }
    }
    gsync(cnt, gen);

    // ---------- phase D: h1 = relu(nm@W1 + b1) -----------------------------
    if (tid < 768) {
      int m = tid >> 2, kq = tid & 3, ko = kq << 8;
      double a[4];
      dotc<4, 256>(nm32 + (size_t)m * 1024 + ko, WL + 16384, ko, a);
#pragma unroll
      for (int j = 0; j < 4; ++j) a[j] = red4(a[j]);
      if (!kq) {
#pragma unroll
        for (int j = 0; j < 4; ++j) {
          int c = cq + j;
          h132[(size_t)m * 1024 + c] = (float)fmax(a[j] + (double)b1[c], 0.0);
        }
      }
    }
    gsync(cnt, gen);

    // ---------- phase E: ml = relu(h1@W2+b2); gate; update; emit -----------
    if (tid < 768) {
      int m = tid >> 2, kq = tid & 3, ko = kq << 8;
      double a[4];
      dotc<4, 256>(h132 + (size_t)m * 1024 + ko, WL + 20480, ko, a);
#pragma unroll
      for (int j = 0; j < 4; ++j) a[j] = red4(a[j]);
      if (!kq) {
        int b = m / 3, s = m - b * 3;
#pragma unroll
        for (int j = 0; j < 4; ++j) {
          int c = cq + j; size_t id = (size_t)m * 1024 + c;
          double ml = fmax(a[j] + (double)b2[c], 0.0);
          double nm2 = nm64[id] + ml;
          double ig = (double)xg32[(size_t)b * 2048 + c]        + (double)g32[(size_t)m * 2048 + c];
          double fg = (double)xg32[(size_t)b * 2048 + 1024 + c] + (double)g32[(size_t)m * 2048 + 1024 + c];
          double old = mem64[id];
          double nv = sigm_d(ig) * tanh(nm2) + sigm_d(fg) * old;
          out[(size_t)(b * T_ + t) * 3072 + s * 1024 + c] = (float)nv;
          mem64[id] = nv; mem32[id] = (float)nv; tmem32[id] = (float)tanh(nv);
        }
      }
    }
    gsync(cnt, gen);
  }
}

// ---------------------------------------------------------------------------
extern "C" void kernel_launch(void* const* d_in, const int* in_sizes, int n_in,
                              void* d_out, int out_size, void* d_ws, size_t ws_size,
                              hipStream_t stream) {
  (void)in_sizes; (void)n_in; (void)out_size;
  const float* inputs = (const float*)d_in[0];
  const float* memory = (const float*)d_in[1];
  const float* Wq = (const float*)d_in[2];  const float* bq = (const float*)d_in[3];
  const float* Wk = (const float*)d_in[4];  const float* bk = (const float*)d_in[5];
  const float* Wv = (const float*)d_in[6];  const float* bv = (const float*)d_in[7];
  const float* Wo = (const float*)d_in[8];  const float* bo = (const float*)d_in[9];
  const float* W1 = (const float*)d_in[10]; const float* b1 = (const float*)d_in[11];
  const float* W2 = (const float*)d_in[12]; const float* b2 = (const float*)d_in[13];
  const float* Wg = (const float*)d_in[14]; const float* bg = (const float*)d_in[15];
  const float* Ug = (const float*)d_in[16]; const float* bu = (const float*)d_in[17];
  float* out = (float*)d_out;

  if (ws_size < (size_t)16 * 1024 * 1024) return;

  char* ws = (char*)d_ws;
  size_t off = 0;
  auto alloc = [&](size_t bytes) -> void* {
    void* p = ws + off; off += (bytes + 255) & ~(size_t)255; return p;
  };
  unsigned* cnt = (unsigned*)alloc(256);
  unsigned* gen = (unsigned*)alloc(256);
  double* mem64 = (double*)alloc((size_t)196608 * 8);
  double* nm64  = (double*)alloc((size_t)196608 * 8);
  float* mem32  = (float*)alloc((size_t)196608 * 4);
  float* tmem32 = (float*)alloc((size_t)196608 * 4);
  float* nm32   = (float*)alloc((size_t)196608 * 4);
  float* o32    = (float*)alloc((size_t)196608 * 4);
  float* h132   = (float*)alloc((size_t)196608 * 4);
  float* q32    = (float*)alloc((size_t)196608 * 4);
  float* km32   = (float*)alloc((size_t)196608 * 4);
  float* vm32   = (float*)alloc((size_t)196608 * 4);
  float* g32    = (float*)alloc((size_t)192 * 2048 * 4);
  float* kx32   = (float*)alloc((size_t)64 * 1024 * 4);
  float* vx32   = (float*)alloc((size_t)64 * 1024 * 4);
  float* xg32   = (float*)alloc((size_t)64 * 2048 * 4);

  k_init<<<768, 256, 0, stream>>>(memory, mem64, mem32, tmem32, cnt, gen, 196608);
  k_fused<<<NBLK, NTHR, 0, stream>>>(inputs, Wq, Wk, Wv, Wo, W1, W2, Wg, Ug,
                                     bq, bk, bv, bo, b1, b2, bg, bu,
                                     mem64, nm64, mem32, tmem32, nm32, o32,
                                     h132, q32, km32, vm32, g32, kx32, vx32,
                                     xg32, cnt, gen, out);
}